// Round 1
// baseline (1975.466 us; speedup 1.0000x reference)
//
#include <hip/hip_runtime.h>
#include <type_traits>
#include <stdint.h>

#define NN 4096
#define TTOT 16777216UL

enum { F_RELU=1, F_ACC=2, F_RS=4, F_BIAS=8 };

struct SelParams {
  unsigned min_ord, max_ord, n_edges, nz_rm, nz_add;
  float lo, M, c0;
  unsigned rm_prefix, rm_k, add_prefix, add_k;
  float t_rm, t_add;
  unsigned n_change;
  unsigned hist[256];
};

__device__ __forceinline__ unsigned ordenc(float x){
  unsigned u = __float_as_uint(x);
  return (u & 0x80000000u) ? ~u : (u | 0x80000000u);
}
__device__ __forceinline__ float orddec(unsigned o){
  unsigned u = (o & 0x80000000u) ? (o ^ 0x80000000u) : ~o;
  return __uint_as_float(u);
}

// ---------------- generic tiled f32 GEMM: C = op(rs*(A@B) [+bias] [+C]) ----
// A: M x K row-major (TA = float or signed char). B: K x N (TB=false) or
// N x K accessed transposed (TB=true). All of M%64, N%64, K%16 == 0.
template<typename TA, bool TB>
__global__ __launch_bounds__(256)
void k_gemm(const TA* __restrict__ A, const float* __restrict__ B,
            float* __restrict__ C, int M, int N, int K,
            const float* __restrict__ rowscale, const float* __restrict__ bias,
            int flags)
{
  __shared__ float As[16][68];
  __shared__ float Bs[16][68];
  const int t  = threadIdx.x;
  const int tx = t & 15, ty = t >> 4;
  const int m0 = blockIdx.y * 64, n0 = blockIdx.x * 64;
  const int mA = t >> 2, kA = (t & 3) * 4;
  float acc[4][4] = {};
  for (int k0 = 0; k0 < K; k0 += 16) {
    if constexpr (std::is_same<TA, float>::value) {
      float4 v = *reinterpret_cast<const float4*>(A + (size_t)(m0+mA)*K + (k0+kA));
      As[kA+0][mA]=v.x; As[kA+1][mA]=v.y; As[kA+2][mA]=v.z; As[kA+3][mA]=v.w;
    } else {
      int u = *reinterpret_cast<const int*>(A + (size_t)(m0+mA)*K + (k0+kA));
      As[kA+0][mA]=(float)(int)(signed char)( u       & 0xff);
      As[kA+1][mA]=(float)(int)(signed char)((u>>8)   & 0xff);
      As[kA+2][mA]=(float)(int)(signed char)((u>>16)  & 0xff);
      As[kA+3][mA]=(float)(int)(signed char)((u>>24)  & 0xff);
    }
    if constexpr (!TB) {
      const int kB = t >> 4, nB = (t & 15) * 4;
      float4 v = *reinterpret_cast<const float4*>(B + (size_t)(k0+kB)*N + (n0+nB));
      Bs[kB][nB+0]=v.x; Bs[kB][nB+1]=v.y; Bs[kB][nB+2]=v.z; Bs[kB][nB+3]=v.w;
    } else {
      const int nB = t >> 2, kB = (t & 3) * 4;
      float4 v = *reinterpret_cast<const float4*>(B + (size_t)(n0+nB)*K + (k0+kB));
      Bs[kB+0][nB]=v.x; Bs[kB+1][nB]=v.y; Bs[kB+2][nB]=v.z; Bs[kB+3][nB]=v.w;
    }
    __syncthreads();
    #pragma unroll
    for (int kk = 0; kk < 16; ++kk) {
      float4 av = *reinterpret_cast<const float4*>(&As[kk][ty*4]);
      float4 bv = *reinterpret_cast<const float4*>(&Bs[kk][tx*4]);
      float a[4]={av.x,av.y,av.z,av.w};
      float b[4]={bv.x,bv.y,bv.z,bv.w};
      #pragma unroll
      for (int i=0;i<4;++i)
        #pragma unroll
        for (int j=0;j<4;++j)
          acc[i][j] = fmaf(a[i], b[j], acc[i][j]);
    }
    __syncthreads();
  }
  #pragma unroll
  for (int i=0;i<4;++i){
    const int m = m0 + ty*4 + i;
    const float rsv = (flags & F_RS) ? rowscale[m] : 1.0f;
    float* cp = C + (size_t)m*N + (n0 + tx*4);
    float o[4];
    #pragma unroll
    for (int j=0;j<4;++j){
      float v = acc[i][j] * rsv;
      if (flags & F_BIAS) v += bias[n0 + tx*4 + j];
      if (flags & F_ACC)  v += cp[j];
      if (flags & F_RELU) v = fmaxf(v, 0.0f);
      o[j] = v;
    }
    *reinterpret_cast<float4*>(cp) = make_float4(o[0],o[1],o[2],o[3]);
  }
}

// ---------------- Z = noise * exp(relu(LP)) + relu(MP) ---------------------
__global__ __launch_bounds__(256)
void k_z(const float* __restrict__ MP, const float* __restrict__ LP,
         const float* __restrict__ noise, float* __restrict__ Z)
{
  int i = blockIdx.x*256 + threadIdx.x;
  float m = fmaxf(MP[i], 0.0f);
  float l = fmaxf(LP[i], 0.0f);
  Z[i] = noise[i]*expf(l) + m;
}

// ---------------- selection stats -----------------------------------------
__global__ __launch_bounds__(256)
void k_initstats(SelParams* p)
{
  int t = threadIdx.x;
  if (t == 0){
    p->min_ord = 0xFFFFFFFFu; p->max_ord = 0u;
    p->n_edges = 0u; p->nz_rm = 0u; p->nz_add = 0u;
  }
  p->hist[t] = 0u;
}

__global__ __launch_bounds__(256)
void k_stats1(const float* __restrict__ L, const float* __restrict__ adj,
              SelParams* __restrict__ p)
{
  unsigned mn=0xFFFFFFFFu, mx=0u, cnt=0u;
  size_t idx = (size_t)blockIdx.x*256 + threadIdx.x;
  const size_t stride = (size_t)gridDim.x*256;
  for (; idx < TTOT; idx += stride){
    const int i = (int)(idx >> 12), j = (int)(idx & 4095);
    const float a = adj[idx];
    if (a != 0.0f) cnt++;
    if (j > i){
      unsigned o = ordenc(L[idx]);
      mn = (o < mn) ? o : mn;
      mx = (o > mx) ? o : mx;
    }
  }
  __shared__ unsigned smn[256], smx[256], sc[256];
  int t = threadIdx.x;
  smn[t]=mn; smx[t]=mx; sc[t]=cnt; __syncthreads();
  for (int s=128; s>0; s>>=1){
    if (t < s){
      smn[t] = (smn[t+s] < smn[t]) ? smn[t+s] : smn[t];
      smx[t] = (smx[t+s] > smx[t]) ? smx[t+s] : smx[t];
      sc[t] += sc[t+s];
    }
    __syncthreads();
  }
  if (t == 0){
    atomicMin(&p->min_ord, smn[0]);
    atomicMax(&p->max_ord, smx[0]);
    atomicAdd(&p->n_edges, sc[0]);
  }
}

__global__ void k_stats2(SelParams* p)
{
  float mnv = orddec(p->min_ord), mxv = orddec(p->max_ord);
  float lo = fminf(mnv, 0.0f), hi = fmaxf(mxv, 0.0f);
  p->lo = lo;
  p->M  = hi - lo;
  p->c0 = (0.0f - lo) / p->M;
  p->n_change = (unsigned)floorf((float)p->n_edges * 1.0f / 2.0f); // CHANGE_FRAC=1.0
}

__global__ __launch_bounds__(256)
void k_countzero(const float* __restrict__ L, const float* __restrict__ adj,
                 SelParams* __restrict__ p)
{
  const float lo = p->lo, M = p->M, c0 = p->c0;
  unsigned zr=0u, za=0u;
  size_t idx = (size_t)blockIdx.x*256 + threadIdx.x;
  const size_t stride = (size_t)gridDim.x*256;
  for (; idx < TTOT; idx += stride){
    const int i = (int)(idx >> 12), j = (int)(idx & 4095);
    const float a = adj[idx];
    const float v = (j > i) ? (L[idx] - lo) / M : c0;
    if (v == 0.0f){ if (a != 0.0f) zr++; else za++; }
  }
  __shared__ unsigned s1[256], s2[256];
  int t = threadIdx.x;
  s1[t]=zr; s2[t]=za; __syncthreads();
  for (int s=128; s>0; s>>=1){
    if (t < s){ s1[t]+=s1[t+s]; s2[t]+=s2[t+s]; }
    __syncthreads();
  }
  if (t == 0){ atomicAdd(&p->nz_rm, s1[0]); atomicAdd(&p->nz_add, s2[0]); }
}

__global__ void k_selinit(SelParams* p)
{
  unsigned nnz_rm  = p->n_edges - p->nz_rm;
  unsigned nnz_add = (unsigned)TTOT - p->n_edges - p->nz_add;
  p->rm_k  = (nnz_rm  < p->n_change) ? nnz_rm  : p->n_change;
  p->add_k = (nnz_add < p->n_change) ? nnz_add : p->n_change;
  p->rm_prefix = 0u; p->add_prefix = 0u;
}

// filter 0: rm candidates (edges, positive keys only). filter 1: add (non-edges).
__global__ __launch_bounds__(256)
void k_hist(const float* __restrict__ L, const float* __restrict__ adj,
            SelParams* __restrict__ p, int shift, int filter)
{
  __shared__ unsigned hs[256];
  const int t = threadIdx.x;
  hs[t] = 0u; __syncthreads();
  const float lo = p->lo, M = p->M, c0 = p->c0;
  const unsigned pref = filter ? p->add_prefix : p->rm_prefix;
  size_t idx = (size_t)blockIdx.x*256 + t;
  const size_t stride = (size_t)gridDim.x*256;
  for (; idx < TTOT; idx += stride){
    const int i = (int)(idx >> 12), j = (int)(idx & 4095);
    const float a = adj[idx];
    const bool edge = (a != 0.0f);
    if (filter == 0){ if (!edge) continue; } else { if (edge) continue; }
    const float v = (j > i) ? (L[idx] - lo) / M : c0;
    const unsigned key = __float_as_uint(v);
    if (filter == 0 && key == 0u) continue;
    if (shift < 24 && (key >> (shift + 8)) != pref) continue;
    atomicAdd(&hs[(key >> shift) & 255u], 1u);
  }
  __syncthreads();
  if (hs[t]) atomicAdd(&p->hist[t], hs[t]);
}

// order 0: k-th smallest (rm); order 1: k-th largest (add)
__global__ __launch_bounds__(256)
void k_scan(SelParams* __restrict__ p, int shift, int order)
{
  __shared__ unsigned h[256];
  int t = threadIdx.x;
  h[t] = p->hist[t];
  __syncthreads();
  if (t == 0){
    unsigned k    = order ? p->add_k : p->rm_k;
    unsigned pref = order ? p->add_prefix : p->rm_prefix;
    unsigned digit = order ? 0u : 255u;
    unsigned cum = 0u;
    if (order == 0){
      for (int d = 0; d < 256; ++d){
        unsigned nc = cum + h[d];
        if (nc >= k){ digit = (unsigned)d; k = k - cum; break; }
        cum = nc;
      }
    } else {
      for (int d = 255; d >= 0; --d){
        unsigned nc = cum + h[d];
        if (nc >= k){ digit = (unsigned)d; k = k - cum; break; }
        cum = nc;
      }
    }
    pref = (pref << 8) | digit;
    if (order){
      p->add_prefix = pref; p->add_k = k;
      if (shift == 0) p->t_add = __uint_as_float(pref);
    } else {
      p->rm_prefix = pref; p->rm_k = k;
      if (shift == 0) p->t_rm = __uint_as_float(pref);
    }
  }
  __syncthreads();
  p->hist[t] = 0u;
}

// ---------------- build adj_new (int8, {-1,0,1,2}, diag=1) ----------------
__global__ __launch_bounds__(256)
void k_apply(const float* __restrict__ L, const float* __restrict__ adj,
             const SelParams* __restrict__ p, signed char* __restrict__ A8)
{
  const int bx = blockIdx.x, by = blockIdx.y;
  if (by > bx) return;
  const float lo=p->lo, M=p->M, c0=p->c0, trm=p->t_rm, tad=p->t_add;
  const int i0 = by*64, j0 = bx*64, t = threadIdx.x;
  if (bx == by){
    __shared__ float Ls[64][65];
    for (int it=0; it<16; ++it){
      int e = it*256 + t; int r = e>>6, c = e&63;
      Ls[r][c] = L[(size_t)(i0+r)*NN + (j0+c)];
    }
    __syncthreads();
    for (int it=0; it<16; ++it){
      int e = it*256 + t; int r = e>>6, c = e&63;
      int i = i0+r, j = j0+c;
      int v;
      if (r == c) v = 1;
      else {
        float a = adj[(size_t)i*NN + j];
        float x = (r < c) ? Ls[r][c] : Ls[c][r];
        float epu = (x - lo) / M;
        bool edge = (a != 0.0f);
        int rmU = (edge && epu >  0.0f && epu <= trm) ? 1 : 0;
        int rmL = (edge && c0  >  0.0f && c0  <= trm) ? 1 : 0;
        int adU = (!edge && epu >= tad) ? 1 : 0;
        int adL = (!edge && c0  >= tad) ? 1 : 0;
        v = (edge ? 1 : 0) - rmU - rmL + adU + adL;
      }
      A8[(size_t)i*NN + j] = (signed char)v;
    }
  } else {
    __shared__ signed char Ts[64][65];
    for (int it=0; it<16; ++it){
      int e = it*256 + t; int r = e>>6, c = e&63;
      int i = i0+r, j = j0+c;
      float a = adj[(size_t)i*NN + j];
      float x = L[(size_t)i*NN + j];
      float epu = (x - lo) / M;
      bool edge = (a != 0.0f);
      int rmU = (edge && epu >  0.0f && epu <= trm) ? 1 : 0;
      int rmL = (edge && c0  >  0.0f && c0  <= trm) ? 1 : 0;
      int adU = (!edge && epu >= tad) ? 1 : 0;
      int adL = (!edge && c0  >= tad) ? 1 : 0;
      int v = (edge ? 1 : 0) - rmU - rmL + adU + adL;
      A8[(size_t)i*NN + j] = (signed char)v;
      Ts[c][r] = (signed char)v;
    }
    __syncthreads();
    for (int it=0; it<16; ++it){
      int e = it*256 + t; int r = e>>6, c = e&63;
      A8[(size_t)(j0+r)*NN + (i0+c)] = Ts[r][c];
    }
  }
}

// ---------------- per-row scale for mean_neigh ----------------------------
__global__ __launch_bounds__(256)
void k_rowsum8(const signed char* __restrict__ A8, float* __restrict__ s_mean)
{
  const int row = blockIdx.x, t = threadIdx.x;
  const int4 w = reinterpret_cast<const int4*>(A8 + (size_t)row*NN)[t];
  int s = 0, a = 0;
  int vs[4] = {w.x, w.y, w.z, w.w};
  #pragma unroll
  for (int q=0; q<4; ++q){
    int u = vs[q];
    #pragma unroll
    for (int b=0; b<4; ++b){
      int c = (int)(signed char)((u >> (8*b)) & 0xff);
      s += c; a += (c < 0) ? -c : c;
    }
  }
  __shared__ int rs_[256], ra_[256];
  rs_[t]=s; ra_[t]=a; __syncthreads();
  for (int st=128; st>0; st>>=1){
    if (t < st){ rs_[t]+=rs_[t+st]; ra_[t]+=ra_[t+st]; }
    __syncthreads();
  }
  if (t == 0){
    float rs = (float)rs_[0], ra = (float)ra_[0];
    float A = fmaxf(ra, 1e-12f);
    s_mean[row] = (1.0f / A) / (rs / A + 1e-7f);
  }
}

// ---------------- row log_softmax (512 cols, in place) --------------------
__global__ __launch_bounds__(256)
void k_lsm(float* __restrict__ X)
{
  const int row = blockIdx.x, t = threadIdx.x;
  float* x = X + (size_t)row*512;
  float v0 = x[t], v1 = x[t+256];
  __shared__ float red[256];
  red[t] = fmaxf(v0, v1); __syncthreads();
  for (int s=128; s>0; s>>=1){
    if (t < s) red[t] = fmaxf(red[t], red[t+s]);
    __syncthreads();
  }
  float m = red[0]; __syncthreads();
  red[t] = expf(v0-m) + expf(v1-m); __syncthreads();
  for (int s=128; s>0; s>>=1){
    if (t < s) red[t] += red[t+s];
    __syncthreads();
  }
  float ls = logf(red[0]);
  x[t]     = (v0 - m) - ls;
  x[t+256] = (v1 - m) - ls;
}

// ---------------- driver ---------------------------------------------------
extern "C" void kernel_launch(void* const* d_in, const int* in_sizes, int n_in,
                              void* d_out, int out_size, void* d_ws, size_t ws_size,
                              hipStream_t stream)
{
  (void)in_sizes; (void)n_in; (void)out_size; (void)ws_size;
  const float* adj_norm = (const float*)d_in[0];
  const float* adj_ori  = (const float*)d_in[1];
  const float* feats    = (const float*)d_in[2];
  const float* img      = (const float*)d_in[3];
  const float* csd_img  = (const float*)d_in[5];
  const float* noise    = (const float*)d_in[6];
  const float* Wb       = (const float*)d_in[7];
  const float* Wm       = (const float*)d_in[8];
  const float* Wl       = (const float*)d_in[9];
  const float* fc1W     = (const float*)d_in[10];
  const float* fc1b     = (const float*)d_in[11];
  const float* fc2W     = (const float*)d_in[12];
  const float* fc2b     = (const float*)d_in[13];

  float* out    = (float*)d_out;
  float* out_pt = out;                 // preds_total 4096x64
  float* out_ft = out + 262144;        // feat_total  4096x512
  float* out_pi = out + 2359296;       // preds_img   4096x64
  float* out_lg = out + 2621440;       // adj_logits  4096x4096

  signed char* adj8 = (signed char*)d_ws;                 // 16 MB
  float* f = (float*)((char*)d_ws + (16u << 20));
  float* P      = f;                 // 4096x512 (reused as 4096x256)
  float* T1     = f + 2097152;       // 4096x256
  float* hidden = f + 3145728;       // 4096x256
  float* HM     = f + 4194304;       // 4096x128
  float* HL     = f + 4718592;       // 4096x128
  float* MP     = f + 5242880;       // 4096x128
  float* LP     = f + 5767168;       // 4096x128
  float* Z      = f + 6291456;       // 4096x128
  float* h1     = f + 6815744;       // 4096x256
  float* s_mean = f + 7864320;       // 4096
  SelParams* sp = (SelParams*)(f + 7868416);

  dim3 B(256);
  auto G = [](int M, int N){ return dim3((unsigned)(N/64), (unsigned)(M/64)); };

  // ep_net
  k_gemm<float,false><<<G(4096,256),B,0,stream>>>(img, Wb, T1, 4096,256,512, nullptr,nullptr,0);
  k_gemm<float,false><<<G(4096,256),B,0,stream>>>(adj_norm, T1, hidden, 4096,256,4096, nullptr,nullptr,0);
  k_gemm<float,false><<<G(4096,128),B,0,stream>>>(hidden, Wm, HM, 4096,128,256, nullptr,nullptr,0);
  k_gemm<float,false><<<G(4096,128),B,0,stream>>>(hidden, Wl, HL, 4096,128,256, nullptr,nullptr,0);
  k_gemm<float,false><<<G(4096,128),B,0,stream>>>(adj_norm, HM, MP, 4096,128,4096, nullptr,nullptr,0);
  k_gemm<float,false><<<G(4096,128),B,0,stream>>>(adj_norm, HL, LP, 4096,128,4096, nullptr,nullptr,0);
  k_z<<<2048,B,0,stream>>>(MP, LP, noise, Z);
  k_gemm<float,true><<<G(4096,4096),B,0,stream>>>(Z, Z, out_lg, 4096,4096,128, nullptr,nullptr,0);

  // edge rewiring: stats + two radix selects, all on device
  k_initstats<<<1,B,0,stream>>>(sp);
  k_stats1<<<2048,B,0,stream>>>(out_lg, adj_ori, sp);
  k_stats2<<<1,1,0,stream>>>(sp);
  k_countzero<<<2048,B,0,stream>>>(out_lg, adj_ori, sp);
  k_selinit<<<1,1,0,stream>>>(sp);
  for (int shift = 24; shift >= 0; shift -= 8){
    k_hist<<<2048,B,0,stream>>>(out_lg, adj_ori, sp, shift, 0);
    k_scan<<<1,B,0,stream>>>(sp, shift, 0);
  }
  for (int shift = 24; shift >= 0; shift -= 8){
    k_hist<<<2048,B,0,stream>>>(out_lg, adj_ori, sp, shift, 1);
    k_scan<<<1,B,0,stream>>>(sp, shift, 1);
  }
  k_apply<<<dim3(64,64),B,0,stream>>>(out_lg, adj_ori, sp, adj8);
  k_rowsum8<<<4096,B,0,stream>>>(adj8, s_mean);

  // nc_net (gsage x2)
  k_gemm<signed char,false><<<G(4096,512),B,0,stream>>>(adj8, feats, P, 4096,512,4096, nullptr,nullptr,0);
  k_gemm<float,false><<<G(4096,256),B,0,stream>>>(feats, fc1W, h1, 4096,256,512, nullptr,fc1b,F_BIAS);
  k_gemm<float,false><<<G(4096,256),B,0,stream>>>(P, fc1W + 512*256, h1, 4096,256,512, s_mean,nullptr,F_ACC|F_RS|F_RELU);
  k_gemm<signed char,false><<<G(4096,256),B,0,stream>>>(adj8, h1, P, 4096,256,4096, nullptr,nullptr,0);
  k_gemm<float,false><<<G(4096,512),B,0,stream>>>(h1, fc2W, out_ft, 4096,512,256, nullptr,fc2b,F_BIAS);
  k_gemm<float,false><<<G(4096,512),B,0,stream>>>(P, fc2W + 256*512, out_ft, 4096,512,256, s_mean,nullptr,F_ACC|F_RS);
  k_lsm<<<4096,B,0,stream>>>(out_ft);

  // heads
  k_gemm<float,true><<<G(4096,64),B,0,stream>>>(out_ft, csd_img, out_pt, 4096,64,512, nullptr,nullptr,0);
  k_gemm<float,true><<<G(4096,64),B,0,stream>>>(img, csd_img, out_pi, 4096,64,512, nullptr,nullptr,0);
}